// Round 6
// baseline (76.623 us; speedup 1.0000x reference)
//
#include <hip/hip_runtime.h>
#include <math.h>

#define N_CELLS_C 100000
#define N_ISO_C 16
#define KP1_C 31
#define BLOCK 256
#define CPB (BLOCK / 4)   // 64 cells/block, 4 lanes (quarters) per cell

typedef float f32x4 __attribute__((ext_vector_type(4)));

// Per-wave index-dtype detect: int64 indices (< 2^17) have all odd int32
// words == 0; int32 random indices make that astronomically unlikely.
__device__ __forceinline__ int idx_shift(const char* idx_bytes) {
    const int lane = threadIdx.x & 63;
    int probe = 0;
    if (lane < 16) probe = ((const int*)idx_bytes)[2 * lane + 1];
    return __any(probe != 0) ? 2 : 3;   // log2(bytes per index)
}

// 4 lanes per cell; lane q owns 16B quarter of the 64B fp32 row, so each
// neighbor gather is one 64B line request (quad-merged). Chunked unroll-6
// keeps VGPR ~60 for high occupancy; nontemporal row loads keep the hot
// unsplice / idx lines resident in L1.
__global__ __launch_bounds__(BLOCK, 6) void cost_kernel(
    const float* __restrict__ unsplice,
    const float* __restrict__ splices,
    const float* __restrict__ unsplice_predict,
    const float* __restrict__ splice_predicts,
    const char*  __restrict__ idx_bytes,
    float*       __restrict__ partials)
{
    const int tid  = threadIdx.x;
    const int q    = tid & 3;
    const int cell = blockIdx.x * CPB + (tid >> 2);
    const int shift = idx_shift(idx_bytes);

    float cost = 0.0f;
    if (cell < N_CELLS_C) {
        const float u_i = unsplice[cell];
        const float uv  = unsplice_predict[cell] - u_i;
        // own row quarter: lanes 0..63 -> 1KB contiguous
        const f32x4 s4  = *(const f32x4*)(splices         + (long long)cell * N_ISO_C + 4 * q);
        const f32x4 sp4 = *(const f32x4*)(splice_predicts + (long long)cell * N_ISO_C + 4 * q);
        const f32x4 v = sp4 - s4;

        float vp = v.x*v.x + v.y*v.y + v.z*v.z + v.w*v.w;
        vp += __shfl_xor(vp, 1);
        vp += __shfl_xor(vp, 2);
        const float vn2 = vp + uv * uv;
        // max_k (dot_k * rsqrt(nn2_k)) * (1/|v|): positive scale commutes with
        // max; zero norms force contribution 0 (ref: denom==0 -> 1, dot==0).
        const float inv_vi = (vn2 > 0.f) ? rsqrtf(vn2) : 0.f;

        const long long base = (long long)cell * KP1_C;
        float maxq = -INFINITY;

        #pragma unroll 1
        for (int c = 0; c < 5; ++c) {        // 5 chunks x 6 neighbors = k=1..30
            int jv[6];
            #pragma unroll
            for (int t = 0; t < 6; ++t)
                jv[t] = *(const int*)(idx_bytes + ((base + 1 + 6 * c + t) << shift));

            f32x4 n4[6]; float un[6];
            #pragma unroll
            for (int t = 0; t < 6; ++t) {
                n4[t] = __builtin_nontemporal_load(
                    (const f32x4*)(splices + (long long)jv[t] * N_ISO_C + 4 * q));
                un[t] = unsplice[jv[t]];
            }
            #pragma unroll
            for (int t = 0; t < 6; ++t) {
                const f32x4 d = n4[t] - s4;
                float dp = v.x*d.x + v.y*d.y + v.z*d.z + v.w*d.w;
                float np = d.x*d.x + d.y*d.y + d.z*d.z + d.w*d.w;
                dp += __shfl_xor(dp, 1);  np += __shfl_xor(np, 1);
                dp += __shfl_xor(dp, 2);  np += __shfl_xor(np, 2);
                const float u   = un[t] - u_i;
                const float dot = dp + uv * u;
                const float nn2 = np + u * u;
                const float rn  = (nn2 > 0.f) ? rsqrtf(nn2) : 0.f;
                maxq = fmaxf(maxq, dot * rn);
            }
        }
        if (q == 0) cost = 1.0f - maxq * inv_vi;   // maxq uniform in quad after butterflies
    }

    // block tree-sum (deterministic)
    for (int off = 32; off > 0; off >>= 1) cost += __shfl_down(cost, off);
    __shared__ float wsum[BLOCK / 64];
    if ((tid & 63) == 0) wsum[tid >> 6] = cost;
    __syncthreads();
    if (tid == 0) {
        float s = 0.f;
        #pragma unroll
        for (int w = 0; w < BLOCK / 64; ++w) s += wsum[w];
        partials[blockIdx.x] = s;
    }
}

__global__ __launch_bounds__(BLOCK) void final_reduce_kernel(
    const float* __restrict__ partials, int nparts, float* __restrict__ out)
{
    float s = 0.0f;
    for (int i = threadIdx.x; i < nparts; i += BLOCK) s += partials[i];
    for (int off = 32; off > 0; off >>= 1) s += __shfl_down(s, off);
    __shared__ float wsum[BLOCK / 64];
    if ((threadIdx.x & 63) == 0) wsum[threadIdx.x >> 6] = s;
    __syncthreads();
    if (threadIdx.x == 0) {
        float t = 0.0f;
        #pragma unroll
        for (int w = 0; w < BLOCK / 64; ++w) t += wsum[w];
        out[0] = t / (float)N_CELLS_C;
    }
}

extern "C" void kernel_launch(void* const* d_in, const int* in_sizes, int n_in,
                              void* d_out, int out_size, void* d_ws, size_t ws_size,
                              hipStream_t stream) {
    const float* unsplice         = (const float*)d_in[0];
    const float* splices          = (const float*)d_in[1];
    const float* unsplice_predict = (const float*)d_in[2];
    const float* splice_predicts  = (const float*)d_in[3];
    const char*  idx_bytes        = (const char*)d_in[4];
    float* out = (float*)d_out;

    float* partials = (float*)d_ws;

    const int nblocks = (N_CELLS_C + CPB - 1) / CPB;   // 1563
    cost_kernel<<<nblocks, BLOCK, 0, stream>>>(
        unsplice, splices, unsplice_predict, splice_predicts,
        idx_bytes, partials);
    final_reduce_kernel<<<1, BLOCK, 0, stream>>>(partials, nblocks, out);
}